// Round 7
// baseline (239.924 us; speedup 1.0000x reference)
//
#include <hip/hip_runtime.h>
#include <hip/hip_bf16.h>
#include <stdint.h>

typedef unsigned short u16;
typedef __attribute__((ext_vector_type(8))) short short8;
typedef __attribute__((ext_vector_type(4))) float f32x4;

#define BATCH 4096
// output region offsets (f32 elements) in d_out: out, h_mix, out_k, h_k
#define OFF_OUT  0
#define OFF_HMIX (BATCH * 256)
#define OFF_OK   (OFF_HMIX + BATCH * 512)
#define OFF_HK   (OFF_OK + BATCH * 256 * 8)

// ws layout (u16/bf16 elements): xb, hb, Wihb, Whhb, Woutb, Tb, Ob (~67 MB)
#define WS_XB   0
#define WS_HB   (2097152)
#define WS_WIH  (4194304)
#define WS_WHH  (6291456)
#define WS_WOUT (8388608)
#define WS_T    (8519680)    // 4096x4096 bf16 plane
#define WS_OB   (25296896)   // 4096x2048 bf16 plane

__device__ __forceinline__ float b2f(u16 v) {
  union { uint32_t u; float f; } c; c.u = ((uint32_t)v) << 16; return c.f;
}
__device__ __forceinline__ u16 f2b(float f) {
  union { float f; uint32_t u; } c; c.f = f;
  uint32_t u = c.u;
  return (u16)((u + 0x7fffu + ((u >> 16) & 1u)) >> 16);  // RNE
}

// async global->LDS, 16B per lane. LDS dest = wave-uniform base + lane*16.
__device__ __forceinline__ void gload16(const u16* g, u16* l) {
  __builtin_amdgcn_global_load_lds(
      (const __attribute__((address_space(1))) void*)g,
      (__attribute__((address_space(3))) void*)l, 16, 0, 0);
}

// ---------------------------------------------------------------------------
// K0: f32 -> bf16 conversion of x, h, W_ih, W_hh, W_out into ws.
// ---------------------------------------------------------------------------
__global__ __launch_bounds__(256) void k0_cvt(
    const float* __restrict__ x, const float* __restrict__ h,
    const float* __restrict__ Wih, const float* __restrict__ Whh,
    const float* __restrict__ Wout, u16* __restrict__ ws) {
  const int i = blockIdx.x * 256 + threadIdx.x;
  const float* src; int j; size_t dst;
  if      (i <  524288) { src = x;    j = i;           dst = WS_XB;   }
  else if (i < 1048576) { src = h;    j = i -  524288; dst = WS_HB;   }
  else if (i < 1572864) { src = Wih;  j = i - 1048576; dst = WS_WIH;  }
  else if (i < 2097152) { src = Whh;  j = i - 1572864; dst = WS_WHH;  }
  else                  { src = Wout; j = i - 2097152; dst = WS_WOUT; }
  const float4 v = ((const float4*)src)[j];
  ushort4 o;
  o.x = f2b(v.x); o.y = f2b(v.y); o.z = f2b(v.z); o.w = f2b(v.w);
  ((ushort4*)(ws + dst))[j] = o;
}

// ---------------------------------------------------------------------------
// K1: Tb[b][k*512+n] = tanh( x[b]·W_ih[k][n] + h[b]·W_hh[k][n] )  (bf16 plane)
// 4096x4096x1024 bf16 GEMM, tanh epilogue. 128x128 tile, BK=64, 4 waves 2x2.
// K-loop LDS XOR-chunk-swizzled (bank-balanced at the data floor).
// K-loop split into 2 phases (x/Wih, h/Whh): branch-free, linear addresses.
// Epilogue: LDS transpose (stride 136 u16) -> coalesced 16B stores.
// ---------------------------------------------------------------------------
__global__ __launch_bounds__(256) void k1_gemm_tanh(
    const u16* __restrict__ xb, const u16* __restrict__ hb,
    const u16* __restrict__ Wih, const u16* __restrict__ Whh,
    u16* __restrict__ Tb) {
  __shared__ u16 S[128 * 136];            // K-loop: As=S[0..8K), Bs=S[8K..16K)
  u16* As = S;                            // 128*64
  u16* Bs = S + 128 * 64;                 // 128*64
  const int tid  = threadIdx.x;
  const int lane = tid & 63;
  const int w    = tid >> 6;
  const int wm   = w >> 1, wn = w & 1;
  const int row0 = blockIdx.x * 128;
  const int col0 = blockIdx.y * 128;   // j = k*512 + n; 128 | 512 so tile is single-k
  const int kk   = col0 >> 9;
  const int nh0  = col0 & 511;
  const int sr   = tid >> 3;                                  // 0..31 staging row
  const int sc   = ((tid & 7) ^ ((tid >> 3) & 7)) * 8;        // swizzled source col
  const int ldsw = (w * 8) * 64;

  f32x4 acc[4][4] = {};
  const int l7 = lane & 7, quad = lane >> 4, rl = lane & 15;

#pragma unroll
  for (int ph = 0; ph < 2; ++ph) {
    // phase-fixed source pointers; addresses advance linearly by 64/iter
    const u16* Ab = (ph == 0) ? (xb + (size_t)(row0 + sr) * 512 + sc)
                              : (hb + (size_t)(row0 + sr) * 512 + sc);
    const u16* Bb = ((ph == 0) ? Wih : Whh)
                    + (size_t)kk * 512 * 512 + (size_t)(nh0 + sr) * 512 + sc;
    for (int kt = 0; kt < 8; ++kt) {
      const int ko = kt * 64;
#pragma unroll
      for (int ro = 0; ro < 4; ++ro) {
        gload16(Ab + (size_t)ro * 32 * 512 + ko, &As[ro * 32 * 64 + ldsw]);
        gload16(Bb + (size_t)ro * 32 * 512 + ko, &Bs[ro * 32 * 64 + ldsw]);
      }
      __syncthreads();
#pragma unroll
      for (int ks = 0; ks < 2; ++ks) {
        short8 af[4], bf[4];
        const int cs = ((ks * 4 + quad) ^ l7) * 8;  // swizzled chunk offset
#pragma unroll
        for (int i = 0; i < 4; ++i)
          af[i] = *(const short8*)&As[(wm * 64 + i * 16 + rl) * 64 + cs];
#pragma unroll
        for (int j = 0; j < 4; ++j)
          bf[j] = *(const short8*)&Bs[(wn * 64 + j * 16 + rl) * 64 + cs];
#pragma unroll
        for (int i = 0; i < 4; ++i)
#pragma unroll
          for (int j = 0; j < 4; ++j)
            acc[i][j] = __builtin_amdgcn_mfma_f32_16x16x32_bf16(af[i], bf[j], acc[i][j], 0, 0, 0);
      }
      __syncthreads();
    }
  }

  // epilogue: tanh -> bf16 -> LDS transpose (stride 136) -> coalesced 16B stores
  const int cl = lane & 15;
#pragma unroll
  for (int i = 0; i < 4; ++i)
#pragma unroll
    for (int j = 0; j < 4; ++j)
#pragma unroll
      for (int r = 0; r < 4; ++r) {
        const int row = wm * 64 + i * 16 + quad * 4 + r;
        const int col = wn * 64 + j * 16 + cl;
        const float v = acc[i][j][r];
        const float e = __expf(2.0f * v);           // tanh, saturating, no NaN
        S[row * 136 + col] = f2b(1.0f - 2.0f / (e + 1.0f));
      }
  __syncthreads();
#pragma unroll
  for (int it = 0; it < 8; ++it) {
    const int idx = it * 256 + tid;   // 0..2047
    const int c = idx & 15;           // 16B chunk in row
    const int r = idx >> 4;           // row 0..127
    *(short8*)&Tb[(size_t)(row0 + r) * 4096 + col0 + c * 8] =
        *(const short8*)&S[r * 136 + c * 8];
  }
}

// ---------------------------------------------------------------------------
// K2: Ob[b][k*256+y] = sum_n Tb[b][k*512+n] * Wout[y][n]   (8 batched GEMMs)
// bf16 in / bf16 out (plane in ws). Same structure + transpose epilogue.
// ---------------------------------------------------------------------------
__global__ __launch_bounds__(256) void k2_gemm_out(
    const u16* __restrict__ Tb, const u16* __restrict__ Wout,
    u16* __restrict__ Ob) {
  __shared__ u16 S[128 * 136];
  u16* As = S;
  u16* Bs = S + 128 * 64;
  const int tid  = threadIdx.x;
  const int lane = tid & 63;
  const int w    = tid >> 6;
  const int wm   = w >> 1, wn = w & 1;
  const int row0 = blockIdx.x * 128;
  const int y0   = blockIdx.y * 128;
  const int kk   = blockIdx.z;
  const int sr   = tid >> 3;
  const int sc   = ((tid & 7) ^ ((tid >> 3) & 7)) * 8;
  const int ldsw = (w * 8) * 64;
  const int l7 = lane & 7, quad = lane >> 4, rl = lane & 15;

  f32x4 acc[4][4] = {};

  const u16* Ab = Tb + (size_t)(row0 + sr) * 4096 + kk * 512 + sc;
  const u16* Bb = Wout + (size_t)(y0 + sr) * 512 + sc;

  for (int kt = 0; kt < 8; ++kt) {
    const int ko = kt * 64;
#pragma unroll
    for (int ro = 0; ro < 4; ++ro) {
      gload16(Ab + (size_t)ro * 32 * 4096 + ko, &As[ro * 32 * 64 + ldsw]);
      gload16(Bb + (size_t)ro * 32 * 512 + ko, &Bs[ro * 32 * 64 + ldsw]);
    }
    __syncthreads();
#pragma unroll
    for (int ks = 0; ks < 2; ++ks) {
      short8 af[4], bf[4];
      const int cs = ((ks * 4 + quad) ^ l7) * 8;
#pragma unroll
      for (int i = 0; i < 4; ++i)
        af[i] = *(const short8*)&As[(wm * 64 + i * 16 + rl) * 64 + cs];
#pragma unroll
      for (int j = 0; j < 4; ++j)
        bf[j] = *(const short8*)&Bs[(wn * 64 + j * 16 + rl) * 64 + cs];
#pragma unroll
      for (int i = 0; i < 4; ++i)
#pragma unroll
        for (int j = 0; j < 4; ++j)
          acc[i][j] = __builtin_amdgcn_mfma_f32_16x16x32_bf16(af[i], bf[j], acc[i][j], 0, 0, 0);
    }
    __syncthreads();
  }

  const int cl = lane & 15;
#pragma unroll
  for (int i = 0; i < 4; ++i)
#pragma unroll
    for (int j = 0; j < 4; ++j)
#pragma unroll
      for (int r = 0; r < 4; ++r) {
        const int row = wm * 64 + i * 16 + quad * 4 + r;
        const int col = wn * 64 + j * 16 + cl;
        S[row * 136 + col] = f2b(acc[i][j][r]);
      }
  __syncthreads();
#pragma unroll
  for (int it = 0; it < 8; ++it) {
    const int idx = it * 256 + tid;
    const int c = idx & 15;
    const int r = idx >> 4;
    *(short8*)&Ob[(size_t)(row0 + r) * 2048 + kk * 256 + y0 + c * 8] =
        *(const short8*)&S[r * 136 + c * 8];
  }
}

// ---------------------------------------------------------------------------
// K3: epilogue. Block b: reads Tb row + Ob row (bf16, ws — L3-hot), writes
// f32 interleaved h_k / out_k + h_mix + out with NON-TEMPORAL stores
// (outputs are never re-read; keep Tb/Ob resident in L2/L3).
// ---------------------------------------------------------------------------
__global__ __launch_bounds__(512) void k3_epi(const float* __restrict__ pi,
                                              const u16* __restrict__ Tb,
                                              const u16* __restrict__ Ob,
                                              float* __restrict__ dout) {
  const int b   = blockIdx.x;
  const int tid = threadIdx.x;

  float pif[8];
#pragma unroll
  for (int k = 0; k < 8; ++k) pif[k] = pi[b * 8 + k];

  float tv[8]; float hm = 0.0f;
#pragma unroll
  for (int k = 0; k < 8; ++k) {
    const float v = b2f(Tb[(size_t)b * 4096 + k * 512 + tid]);
    tv[k] = v; hm += pif[k] * v;
  }
  f32x4* tw = (f32x4*)&dout[OFF_HK + (size_t)b * 4096 + tid * 8];
  f32x4 t0 = {tv[0], tv[1], tv[2], tv[3]};
  f32x4 t1 = {tv[4], tv[5], tv[6], tv[7]};
  __builtin_nontemporal_store(t0, tw);
  __builtin_nontemporal_store(t1, tw + 1);
  __builtin_nontemporal_store(hm, &dout[OFF_HMIX + (size_t)b * 512 + tid]);

  if (tid < 256) {
    float ov[8]; float om = 0.0f;
#pragma unroll
    for (int k = 0; k < 8; ++k) {
      const float v = b2f(Ob[(size_t)b * 2048 + k * 256 + tid]);
      ov[k] = v; om += pif[k] * v;
    }
    f32x4* ow = (f32x4*)&dout[OFF_OK + (size_t)b * 2048 + tid * 8];
    f32x4 o0 = {ov[0], ov[1], ov[2], ov[3]};
    f32x4 o1 = {ov[4], ov[5], ov[6], ov[7]};
    __builtin_nontemporal_store(o0, ow);
    __builtin_nontemporal_store(o1, ow + 1);
    __builtin_nontemporal_store(om, &dout[OFF_OUT + (size_t)b * 256 + tid]);
  }
}

extern "C" void kernel_launch(void* const* d_in, const int* in_sizes, int n_in,
                              void* d_out, int out_size, void* d_ws, size_t ws_size,
                              hipStream_t stream) {
  const float* x    = (const float*)d_in[0];
  const float* h    = (const float*)d_in[1];
  const float* pi   = (const float*)d_in[2];
  const float* Wih  = (const float*)d_in[3];
  const float* Whh  = (const float*)d_in[4];
  const float* Wout = (const float*)d_in[5];
  float* out = (float*)d_out;
  u16* ws  = (u16*)d_ws;

  k0_cvt<<<dim3(8320), 256, 0, stream>>>(x, h, Wih, Whh, Wout, ws);
  k1_gemm_tanh<<<dim3(32, 32), 256, 0, stream>>>(
      ws + WS_XB, ws + WS_HB, ws + WS_WIH, ws + WS_WHH, ws + WS_T);
  k2_gemm_out<<<dim3(32, 2, 8), 256, 0, stream>>>(ws + WS_T, ws + WS_WOUT, ws + WS_OB);
  k3_epi<<<dim3(BATCH), 512, 0, stream>>>(pi, ws + WS_T, ws + WS_OB, out);
}